// Round 19
// baseline (926.705 us; speedup 1.0000x reference)
//
#include <hip/hip_runtime.h>

#define PI_D 3.141592653589793238462643383279502884
#define WAVE_SYNC() asm volatile("s_waitcnt lgkmcnt(0)" ::: "memory")

// B_IN=30, B_L1=15, B_OUT=5; K_IN=1, K_L1=50, K_L2=100, N_CLS=10
// ---------------- workspace layout (float offsets) ----------------
constexpr int OFF_C60   = 0;
constexpr int OFF_S60   = 60;
constexpr int OFF_C30   = 120;
constexpr int OFF_S30   = 150;
constexpr int OFF_C10   = 180;
constexpr int OFF_S10   = 190;
constexpr int OFF_WINT  = 200;                          // 10
constexpr int OFF_DS2   = 256;                          // [l=15][m=29][k=60] = 26100
constexpr int OFF_DINV1 = OFF_DS2   + 26100;            // [k=30][l=15][m=29][n=29] = 378450
constexpr int OFF_DSO3F = OFF_DINV1 + 378450;           // [l=5][m=9][9][k=30] = 12150
constexpr int OFF_DOUT  = OFF_DSO3F + 12150;            // [k2=10][l=5][9][9] = 4050
constexpr int OFF_FSEL  = OFF_DOUT  + 4050;             // f2 [b=32][k=60][m=29] = 55680 f2
constexpr int OFF_XHAT  = OFF_FSEL  + 55680*2;          // f2 [b=32][l=15][m=29] = 13920 f2
constexpr int OFF_XHAT2 = OFF_XHAT  + 13920*2;          // f2 [l=5][288][450]    = 648000 f2
constexpr int OFF_FEATS = OFF_XHAT2 + 648000*2;         // [b=32][g=100] = 3200
constexpr int OFF_PSIT  = OFF_FEATS + 3200;             // f2 [g=50][l*29+n=435] = 21750 f2 (conj)
constexpr int OFF_R     = OFF_PSIT  + 21750*2;
// region R is reused:
//   FW    (f2 [b=32][fl=25][k=30][45] = 1,080,000 f2) live during k_s2so3/k_xhat2 passes
//   YHAT2 (f2 [l=5][288][900]         = 1,296,000 f2) live from k_yhat2 onward
constexpr int OFF_FW    = OFF_R;
constexpr int OFF_YH2   = OFF_R;
constexpr size_t WS_NEED = (size_t)(OFF_R + 2592000) * 4;   // ~18.4 MB

// ---------------- init: Wigner-d tables (double precision) ----------------
__constant__ double FCT[30] = {
  1.0, 1.0, 2.0, 6.0, 24.0, 120.0, 720.0, 5040.0, 40320.0, 362880.0,
  3628800.0, 39916800.0, 479001600.0, 6227020800.0, 87178291200.0,
  1307674368000.0, 20922789888000.0, 355687428096000.0, 6402373705728000.0,
  121645100408832000.0, 2432902008176640000.0, 51090942171709440000.0,
  1124000727777607680000.0, 25852016738884976640000.0,
  620448401733239439360000.0, 15511210043330985984000000.0,
  403291461126605635584000000.0, 10888869450418352160768000000.0,
  304888344611713860501504000000.0, 8841761993739701954543616000000.0 };

__device__ __forceinline__ int iabs_(int x)        { return x < 0 ? -x : x; }
__device__ __forceinline__ int imax_(int a, int b) { return a > b ? a : b; }
__device__ __forceinline__ int imin_(int a, int b) { return a < b ? a : b; }

__device__ double ipowd(double x, int e) {
  double r = 1.0;
  for (int i = 0; i < e; ++i) r *= x;
  return r;
}

// Wigner small-d element d^l_{mp,mm}(beta).
// c/s powers via recurrence P_{t+1} = P_t * (s^2/c^2) — one ipowd pair
// per ELEMENT instead of per t-term (verified R18).
__device__ double wig_d(int l, int mp, int mm, double beta) {
  double c = cos(0.5 * beta), s = sin(0.5 * beta);
  double pref = sqrt(FCT[l+mp] * FCT[l-mp] * FCT[l+mm] * FCT[l-mm]);
  int t0 = imax_(0, mm - mp), t1 = imin_(l + mm, l - mp);
  if (t0 > t1) return 0.0;
  double P = ipowd(c, 2*l + mm - mp - 2*t0) * ipowd(s, mp - mm + 2*t0);
  double ratio = (s*s) / (c*c);
  double acc = 0.0;
  for (int t = t0; t <= t1; ++t) {
    double term = P / (FCT[l+mm-t] * FCT[t] * FCT[mp-mm+t] * FCT[l-mp-t]);
    acc += ((mp - mm + t) & 1) ? -term : term;
    P *= ratio;
  }
  return pref * acc;
}

// Driscoll-Healy quadrature weight for bandwidth bq, sample k
__device__ double dh_w(int bq, int k) {
  double beta = PI_D * (2*k + 1) / (4.0 * bq);
  double ssum = 0.0;
  for (int j = 0; j < bq; ++j) ssum += sin((2*j + 1) * beta) / (2*j + 1);
  return (2.0 / bq) * sin(beta) * ssum;
}

// ---- one merged init kernel: ds2 | dinv1 | dso3f | dout | psit | trig ----
constexpr int SEG_DS2   = 0;
constexpr int SEG_DINV1 = SEG_DS2   + 26100;
constexpr int SEG_DSO3F = SEG_DINV1 + 378450;
constexpr int SEG_DOUT  = SEG_DSO3F + 12150;
constexpr int SEG_PSIT  = SEG_DOUT  + 4050;
constexpr int SEG_TRIG  = SEG_PSIT  + 21750;
constexpr int SEG_END   = SEG_TRIG  + 128;

__global__ void k_init_all(const float* __restrict__ ps2r,
                           const float* __restrict__ ps2i, float* W) {
  int id = blockIdx.x*256 + threadIdx.x;
  if (id >= SEG_END) return;
  if (id < SEG_DINV1) {            // D_S2[l][m][k]
    int t = id - SEG_DS2;
    int k = t % 60, m = (t/60) % 29, l = t/1740;
    int mp = m - 14;
    float v = 0.f;
    if (iabs_(mp) <= l) {
      double beta = PI_D * (2*k + 1) / 120.0;
      v = (float)(wig_d(l, mp, 0, beta) * dh_w(30, k) * (2.0*PI_D/60.0));
    }
    W[OFF_DS2 + t] = v;
  } else if (id < SEG_DSO3F) {     // DINV1[k][l][m][n]
    int t = id - SEG_DINV1;
    int n = t % 29, m = (t/29) % 29, l = (t/841) % 15, k = t/12615;
    int mp = m - 14, mm = n - 14;
    float v = 0.f;
    if (imax_(iabs_(mp), iabs_(mm)) <= l) {
      double beta = PI_D * (2*k + 1) / 60.0;
      v = (float)(wig_d(l, mp, mm, beta) * (2.0*l + 1.0) / (8.0*PI_D*PI_D));
    }
    W[OFF_DINV1 + t] = v;
  } else if (id < SEG_DOUT) {      // DSO3F[l][m][n][k]
    int t = id - SEG_DSO3F;
    int k = t % 30, n = (t/30) % 9, m = (t/270) % 9, l = t/2430;
    int mp = m - 4, mm = n - 4;
    float v = 0.f;
    if (imax_(iabs_(mp), iabs_(mm)) <= l) {
      double beta = PI_D * (2*k + 1) / 60.0;
      double sc = 2.0*PI_D/30.0;
      v = (float)(wig_d(l, mp, mm, beta) * dh_w(15, k) * sc * sc);
    }
    W[OFF_DSO3F + t] = v;
  } else if (id < SEG_PSIT) {      // DOUT[k2][l][m][n]
    int t = id - SEG_DOUT;
    int n = t % 9, m = (t/9) % 9, l = (t/81) % 5, k2 = t/405;
    int mp = m - 4, mm = n - 4;
    float v = 0.f;
    if (imax_(iabs_(mp), iabs_(mm)) <= l) {
      double beta = PI_D * (2*k2 + 1) / 20.0;
      v = (float)(wig_d(l, mp, mm, beta) * (2.0*l + 1.0) / (8.0*PI_D*PI_D));
    }
    W[OFF_DOUT + t] = v;
  } else if (id < SEG_TRIG) {      // PsiT[g][l*29+n] = conj(psi_s2)
    int t = id - SEG_PSIT;
    int g = t / 435, i = t % 435;
    ((float2*)(W + OFF_PSIT))[t] = make_float2(ps2r[i*50 + g], -ps2i[i*50 + g]);
  } else {                         // trig tables + W_INT
    int t = id - SEG_TRIG;
    if (t < 60) { W[OFF_C60+t] = (float)cos(2.0*PI_D*t/60.0); W[OFF_S60+t] = (float)sin(2.0*PI_D*t/60.0); }
    if (t < 30) { W[OFF_C30+t] = (float)cos(2.0*PI_D*t/30.0); W[OFF_S30+t] = (float)sin(2.0*PI_D*t/30.0); }
    if (t < 10) {
      W[OFF_C10+t] = (float)cos(2.0*PI_D*t/10.0); W[OFF_S10+t] = (float)sin(2.0*PI_D*t/10.0);
      double sc = 2.0*PI_D/10.0;
      W[OFF_WINT+t] = (float)(dh_w(5, t) * sc * sc);
    }
  }
}

// ---------------- pipeline ----------------
// K1a: Fsel[b][k][m] = sum_p x[b,k,p] * exp(-2pi*i*(m-14)*p/60)
__global__ void k_fsel(const float* __restrict__ x, float* W) {
  int id = blockIdx.x*256 + threadIdx.x;
  if (id >= 32*60*29) return;
  int m = id % 29, k = (id/29) % 60, b = id/1740;
  const float* c60 = W + OFF_C60;
  const float* s60 = W + OFF_S60;
  const float* xr = x + (b*60 + k)*60;
  int d = m - 14, q = 0;
  float ar = 0.f, ai = 0.f;
  for (int p = 0; p < 60; ++p) {
    float xv = xr[p];
    ar += xv * c60[q]; ai -= xv * s60[q];
    q += d; if (q >= 60) q -= 60; if (q < 0) q += 60;
  }
  ((float2*)(W + OFF_FSEL))[id] = make_float2(ar, ai);
}

// K1b: xhat[b][l][m] = sum_k D_S2[l][m][k] * Fsel[b][k][m]
__global__ void k_xhat(float* W) {
  int id = blockIdx.x*256 + threadIdx.x;
  if (id >= 32*15*29) return;
  int m = id % 29, l = (id/29) % 15, b = id/435;
  const float* D = W + OFF_DS2 + (l*29 + m)*60;
  const float2* F = (const float2*)(W + OFF_FSEL) + b*1740 + m;
  float ar = 0.f, ai = 0.f;
  for (int k = 0; k < 60; ++k) {
    float d = D[k]; float2 fv = F[k*29];
    ar += d*fv.x; ai += d*fv.y;
  }
  ((float2*)(W + OFF_XHAT))[id] = make_float2(ar, ai);
}

// K2: wave-private fused plane processor, radix-2 (30 = 2x15) in BOTH inverse
//  DFTs (R11 math, verified). FW stores ONLY Hermitian rows 4..8 (45 f2/plane)
//  — mirror rows reconstructed in k_xhat2 by conj; grid = (flgrp, b, k).
__global__ void __launch_bounds__(192, 5) k_s2so3(float* W, int g_base) {
  __shared__ float2 Xs[435];          // xhat[b][l][m]
  __shared__ float2 tw30s[30];        // w^q = (cos, sin)(2*pi*q/30)
  __shared__ float2 ABw[3][900];      // per-wave [r=15][p=2][m=30]; overlaid by Fa later
  int tid = threadIdx.x;
  int lane = tid & 63, w = tid >> 6;
  int k = blockIdx.z;                 // 0..29 (slowest -> Dg locality)
  int b = blockIdx.y;                 // 0..31
  int fl = blockIdx.x * 3 + w;        // 0..26; >=25 idle
  int g = g_base + fl;

  {
    const float2* XH = (const float2*)(W + OFF_XHAT);
    for (int i = tid; i < 435; i += 192) Xs[i] = XH[b*435 + i];
    if (tid < 30) tw30s[tid] = make_float2(W[OFF_C30+tid], W[OFF_S30+tid]);
  }
  __syncthreads();                    // the only block barrier
  if (fl >= 25) return;               // idle wave-slots exit

  const float* __restrict__ Dg = W + OFF_DINV1 + k*12615;               // L2/L1
  const float2* __restrict__ Qg = (const float2*)(W + OFF_PSIT) + g*435; // L2
  float2* ABs = ABw[w];

  // --- AB phase: unit e = m*15 + r computes G pair (n1=r+14, n2=r-1),
  //     stores A = g1+g2 at [r][0][m], Btilde = (g1-g2)*w^r at [r][1][m].
  //     m=29 and r=0's g2 vanish naturally via lmin >= 15 (empty l-loop).
  {
    int m = lane / 15, r = lane - (lane/15)*15;
    for (int e = lane; e < 450; e += 64) {
      int am = iabs_(m - 14);
      int n1 = r + 14;
      float g1r = 0.f, g1i = 0.f;
      int lmin1 = imax_(am, r);
      for (int l = lmin1; l < 15; ++l) {
        float d = Dg[l*841 + m*29 + n1];
        float2 X = Xs[l*29 + m];
        float2 Q = Qg[l*29 + n1];
        g1r += d*(X.x*Q.x - X.y*Q.y);
        g1i += d*(X.x*Q.y + X.y*Q.x);
      }
      int n2 = r - 1;                       // invalid for r=0, but loop is empty then
      float g2r = 0.f, g2i = 0.f;
      int lmin2 = imax_(am, 15 - r);
      for (int l = lmin2; l < 15; ++l) {
        float d = Dg[l*841 + m*29 + n2];
        float2 X = Xs[l*29 + m];
        float2 Q = Qg[l*29 + n2];
        g2r += d*(X.x*Q.x - X.y*Q.y);
        g2i += d*(X.x*Q.y + X.y*Q.x);
      }
      float2 tw = tw30s[r];
      float br = g1r - g2r, bi = g1i - g2i;
      ABs[(r*2+0)*30 + m] = make_float2(g1r + g2r, g1i + g2i);
      ABs[(r*2+1)*30 + m] = make_float2(br*tw.x - bi*tw.y, br*tw.y + bi*tw.x);
      r += 4; m += 4; if (r >= 15) { r -= 15; m += 1; }   // 64 = 4*15 + 4
    }
  }
  WAVE_SYNC();

  // --- T phase: lane (j = lane>>1, half = lane&1); j = 2t + p ---
  int j = lane >> 1, half = lane & 1;
  bool act = (j < 30);
  int p = j & 1, t = j >> 1;
  int m0 = half * 15;                 // half0: m 0..14, half1: m 15..29 (29 = zero)
  const float2* Crow = ABs + p*30 + m0;
  float tr[15], ti[15];
  #pragma unroll
  for (int mi = 0; mi < 15; ++mi) { tr[mi] = 0.f; ti[mi] = 0.f; }
  if (act) {
    int q = 0, step = 2*t;            // nu^{tr} = tw30s[(2tr) mod 30]
    for (int r = 0; r < 15; ++r) {
      float2 tw = tw30s[q];
      #pragma unroll
      for (int mi = 0; mi < 15; ++mi) {
        float2 cv = Crow[r*60 + mi];
        tr[mi] += cv.x*tw.x - cv.y*tw.y;
        ti[mi] += cv.x*tw.y + cv.y*tw.x;
      }
      q += step; if (q >= 30) q -= 30;
    }
  }

  // --- exchange + m-direction radix-2 pre-combine (pairs align at same reg) ---
  // half0 builds Ah[r], half1 builds Bh[r]*w^r; r=0 term = T[14] (half0 reg 14)
  float cr[15], ci[15];
  if (act) {
    float sgn = half ? -1.f : 1.f;
    #pragma unroll
    for (int i = 0; i < 14; ++i) {
      float otr = __shfl_xor(tr[i], 1);
      float oti = __shfl_xor(ti[i], 1);
      float vr = fmaf(sgn, otr, tr[i]) * (half ? -sgn : 1.f); // half0: tr+otr; half1: tr-otr
      float vi = fmaf(sgn, oti, ti[i]) * (half ? -sgn : 1.f);
      float2 twc = half ? tw30s[i+1] : make_float2(1.f, 0.f);
      cr[i+1] = vr*twc.x - vi*twc.y;
      ci[i+1] = vr*twc.y + vi*twc.x;
    }
    float otr14 = __shfl_xor(tr[14], 1);
    float oti14 = __shfl_xor(ti[14], 1);
    cr[0] = half ? otr14 : tr[14];
    ci[0] = half ? oti14 : ti[14];
  } else {
    #pragma unroll
    for (int i = 0; i < 15; ++i) { cr[i] = 0.f; ci[i] = 0.f; }
  }

  // --- h (own parity: a = 2s + half) + Fa partials for m2 = 4..8 ---
  float far[5], fai[5];
  #pragma unroll
  for (int u = 0; u < 5; ++u) { far[u] = 0.f; fai[u] = 0.f; }
  if (act) {
    for (int s = 0; s < 15; ++s) {
      int a = 2*s + half;
      float hp = 0.f;
      int q = 0, step = 2*s;
      #pragma unroll
      for (int r = 0; r < 15; ++r) {
        float2 tw = tw30s[q];
        hp += cr[r]*tw.x - ci[r]*tw.y;
        q += step; if (q >= 30) q -= 30;
      }
      float hv = fmaxf(hp, 0.f);
      int q2 = 0;                       // (m2-4)*a mod 30, step a
      #pragma unroll
      for (int u = 0; u < 5; ++u) {
        float2 tw = tw30s[q2];
        far[u] += hv*tw.x;
        fai[u] -= hv*tw.y;
        q2 += a; if (q2 >= 30) q2 -= 30;
      }
    }
    // combine even/odd-a partials across the lane pair
    #pragma unroll
    for (int u = 0; u < 5; ++u) {
      far[u] += __shfl_xor(far[u], 1);
      fai[u] += __shfl_xor(fai[u], 1);
    }
  }
  WAVE_SYNC();   // all reads of ABs done; safe to overlay Fa

  // --- write Fa rows 4..8 (overlay on dead ABs region) ---
  float2* Fas = ABs;
  if (act && half == 0) {
    #pragma unroll
    for (int u = 0; u < 5; ++u)
      Fas[(4 + u)*30 + j] = make_float2(far[u], fai[u]);
  }
  WAVE_SYNC();

  // --- FW rows 4..8 only (45 entries); mirror handled in k_xhat2 ---
  float2* FW = (float2*)(W + OFF_FW);
  size_t pbase = ((size_t)(b*25 + fl)*30 + k)*45;
  if (lane < 45) {
    int m2 = 4 + lane/9, n2 = lane % 9;
    int d = (n2 - 4 + 30) % 30, q = 0;
    float fr = 0.f, fi = 0.f;
    for (int jj = 0; jj < 30; ++jj) {
      float2 fv = Fas[m2*30 + jj];
      float2 tw = tw30s[q];
      fr += fv.x*tw.x + fv.y*tw.y;
      fi += fv.y*tw.x - fv.x*tw.y;
      q += d; if (q >= 30) q -= 30;
    }
    FW[pbase + lane] = make_float2(fr, fi);
  }
}

// K3: xhat2[l][b*9+m2][f*9+n2] = sum_k DSO3F[l][m2][n2][k] * FW(k)[m2][n2]
//  FW stores rows 4..8 only; m2<4 reconstructed via FW[m2][n2]=conj(FW[8-m2][8-n2]).
__global__ void k_xhat2(float* W, int g_base) {
  int id = blockIdx.x*256 + threadIdx.x;
  if (id >= 324000) return;
  int n2 = id % 9, fl = (id/9) % 25, m2 = (id/225) % 9, b = (id/2025) % 32, l = id/64800;
  int f = g_base + fl;
  const float* D = W + OFF_DSO3F + (l*81 + m2*9 + n2)*30;
  bool mir = (m2 < 4);
  int ms = mir ? (4 - m2) : (m2 - 4);     // storage row (0..4 maps m2 4..8)
  int cs = mir ? (8 - n2) : n2;
  const float2* FWp = (const float2*)(W + OFF_FW)
                    + (size_t)(b*25 + fl)*30*45 + ms*9 + cs;
  float ar = 0.f, ai = 0.f;
  for (int k = 0; k < 30; ++k) {
    float d = D[k]; float2 fv = FWp[(size_t)k*45];
    ar += d*fv.x; ai += d*fv.y;
  }
  if (mir) ai = -ai;
  ((float2*)(W + OFF_XHAT2))[(l*288 + b*9 + m2)*450 + f*9 + n2] = make_float2(ar, ai);
}

// K4: per-l complex GEMM C[288][900] = A[288][450] * B[450][900]
//  R19: 64x64 C-tile, 4x4 f2 accumulators per thread (0.5 LDS reads/cmac vs
//  0.75 at 32x64/2x4). Row guard at 288 (grid y=5 covers 320 rows).
__global__ void __launch_bounds__(256) k_yhat2(const float* __restrict__ p3r,
                                               const float* __restrict__ p3i,
                                               float* W) {
  __shared__ float2 As[64][30];
  __shared__ float2 Bs[30][64];
  int l  = blockIdx.z;
  int r0 = blockIdx.y * 64;
  int c0 = blockIdx.x * 64;
  int tid = threadIdx.x;
  const float2* A = (const float2*)(W + OFF_XHAT2) + (size_t)l*288*450;
  float2*       C = (float2*)(W + OFF_YH2)         + (size_t)l*288*900;
  int tr = tid / 16, tc = tid % 16;     // 16x16 thread grid, 4x4 outputs each
  float2 acc[4][4];
  #pragma unroll
  for (int i = 0; i < 4; ++i)
    #pragma unroll
    for (int j = 0; j < 4; ++j) acc[i][j] = make_float2(0.f, 0.f);

  for (int k0 = 0; k0 < 450; k0 += 30) {
    for (int e = tid; e < 1920; e += 256) {
      int i = e / 30, kk = e % 30;
      int r = r0 + i;
      As[i][kk] = (r < 288) ? A[(size_t)r*450 + k0 + kk] : make_float2(0.f, 0.f);
    }
    for (int e = tid; e < 1920; e += 256) {
      int kkr = e / 64, j = e % 64;
      int c = k0 + kkr;
      int f = c / 9, kk = c % 9;
      int cc = c0 + j;
      float2 v = make_float2(0.f, 0.f);
      if (cc < 900) {
        int n = cc / 100, g = cc % 100;
        int idx = (((l*9 + n)*9 + kk)*50 + f)*100 + g;
        v = make_float2(p3r[idx], -p3i[idx]);
      }
      Bs[kkr][j] = v;
    }
    __syncthreads();
    #pragma unroll 2
    for (int kk = 0; kk < 30; ++kk) {
      float2 aa[4], bb[4];
      #pragma unroll
      for (int i = 0; i < 4; ++i) aa[i] = As[tr*4 + i][kk];
      #pragma unroll
      for (int j = 0; j < 4; ++j) bb[j] = Bs[kk][tc*4 + j];
      #pragma unroll
      for (int i = 0; i < 4; ++i)
        #pragma unroll
        for (int j = 0; j < 4; ++j) {
          acc[i][j].x += aa[i].x*bb[j].x - aa[i].y*bb[j].y;
          acc[i][j].y += aa[i].x*bb[j].y + aa[i].y*bb[j].x;
        }
    }
    __syncthreads();
  }
  #pragma unroll
  for (int i = 0; i < 4; ++i) {
    int r = r0 + tr*4 + i;
    if (r < 288) {
      #pragma unroll
      for (int j = 0; j < 4; ++j) {
        int cc = c0 + tc*4 + j;
        if (cc < 900) C[(size_t)r*900 + cc] = acc[i][j];
      }
    }
  }
}

// K5: per (b,g): G2 -> 9x9->10x10 ifft2 -> relu -> weighted sum over (k2,a,j)
__global__ void __launch_bounds__(128) k_so3out(float* W) {
  __shared__ float2 Ys[405];
  __shared__ float2 G2s[81];
  __shared__ float2 T2s[90];
  __shared__ float  red[128];
  __shared__ float  c10s[10], s10s[10];
  int g = blockIdx.x, b = blockIdx.y, tid = threadIdx.x;
  const float2* C = (const float2*)(W + OFF_YH2);
  for (int e = tid; e < 405; e += 128) {
    int l = e / 81, r = e % 81, m = r / 9, n = r % 9;
    Ys[e] = C[((size_t)l*288 + b*9 + m)*900 + n*100 + g];
  }
  if (tid < 10) { c10s[tid] = W[OFF_C10+tid]; s10s[tid] = W[OFF_S10+tid]; }
  __syncthreads();
  float pacc = 0.f;
  for (int k2 = 0; k2 < 10; ++k2) {
    float wi = W[OFF_WINT + k2];
    if (tid < 81) {
      int m = tid / 9, n = tid % 9;
      int lmin = imax_(iabs_(m-4), iabs_(n-4));
      float ar = 0.f, ai = 0.f;
      for (int l = lmin; l < 5; ++l) {
        float d = W[OFF_DOUT + (k2*5 + l)*81 + tid];
        float2 y = Ys[l*81 + tid];
        ar += d*y.x; ai += d*y.y;
      }
      G2s[tid] = make_float2(ar, ai);
    }
    __syncthreads();
    if (tid < 90) {
      int m = tid / 10, j = tid % 10;
      int q = ((-4*j) % 10 + 10) % 10;
      float tr = 0.f, ti = 0.f;
      for (int n = 0; n < 9; ++n) {
        float2 gv = G2s[m*9 + n];
        float c = c10s[q], s = s10s[q];
        tr += gv.x*c - gv.y*s; ti += gv.x*s + gv.y*c;
        q += j; if (q >= 10) q -= 10;
      }
      T2s[tid] = make_float2(tr, ti);
    }
    __syncthreads();
    if (tid < 100) {
      int a = tid / 10, j = tid % 10;
      int q = ((-4*a) % 10 + 10) % 10;
      float hv = 0.f;
      for (int m = 0; m < 9; ++m) {
        float2 tv = T2s[m*10 + j];
        hv += tv.x*c10s[q] - tv.y*s10s[q];
        q += a; if (q >= 10) q -= 10;
      }
      pacc += wi * fmaxf(hv, 0.f);
    }
    __syncthreads();
  }
  red[tid] = pacc;
  __syncthreads();
  for (int s = 64; s > 0; s >>= 1) {
    if (tid < s) red[tid] += red[tid + s];
    __syncthreads();
  }
  if (tid == 0) W[OFF_FEATS + b*100 + g] = red[0];
}

// K6: out[b][c] = bias[c] + sum_g feats[b][g] * w[c][g]
__global__ void k_out(const float* W, const float* __restrict__ w,
                      const float* __restrict__ bias, float* out) {
  int tid = threadIdx.x;
  if (tid >= 320) return;
  int bb = tid / 10, c = tid % 10;
  float acc = bias[c];
  const float* f  = W + OFF_FEATS + bb*100;
  const float* wr = w + c*100;
  for (int g = 0; g < 100; ++g) acc += f[g]*wr[g];
  out[tid] = acc;
}

extern "C" void kernel_launch(void* const* d_in, const int* in_sizes, int n_in,
                              void* d_out, int out_size, void* d_ws, size_t ws_size,
                              hipStream_t stream) {
  (void)in_sizes; (void)n_in; (void)out_size;
  if (ws_size < WS_NEED) return;  // fail loud: output stays poisoned
  const float* x    = (const float*)d_in[0];
  const float* p2r  = (const float*)d_in[1];
  const float* p2i  = (const float*)d_in[2];
  const float* p3r  = (const float*)d_in[3];
  const float* p3i  = (const float*)d_in[4];
  const float* wlin = (const float*)d_in[5];
  const float* blin = (const float*)d_in[6];
  float* W   = (float*)d_ws;
  float* out = (float*)d_out;

  k_init_all <<<(SEG_END + 255)/256, 256, 0, stream>>>(p2r, p2i, W);
  k_fsel     <<<218, 256, 0, stream>>>(x, W);
  k_xhat     <<<55,  256, 0, stream>>>(W);
  for (int gb = 0; gb < 50; gb += 25) {
    k_s2so3 <<<dim3(9, 32, 30), 192, 0, stream>>>(W, gb);
    k_xhat2 <<<1266, 256, 0, stream>>>(W, gb);
  }
  k_yhat2  <<<dim3(15, 5, 5), 256, 0, stream>>>(p3r, p3i, W);
  k_so3out <<<dim3(100, 32), 128, 0, stream>>>(W);
  k_out    <<<1, 320, 0, stream>>>(W, wlin, blin, out);
}

// Round 20
// 914.832 us; speedup vs baseline: 1.0130x; 1.0130x over previous
//
#include <hip/hip_runtime.h>

#define PI_D 3.141592653589793238462643383279502884
#define WAVE_SYNC() asm volatile("s_waitcnt lgkmcnt(0)" ::: "memory")

// B_IN=30, B_L1=15, B_OUT=5; K_IN=1, K_L1=50, K_L2=100, N_CLS=10
// ---------------- workspace layout (float offsets) ----------------
constexpr int OFF_C60   = 0;
constexpr int OFF_S60   = 60;
constexpr int OFF_C30   = 120;
constexpr int OFF_S30   = 150;
constexpr int OFF_C10   = 180;
constexpr int OFF_S10   = 190;
constexpr int OFF_WINT  = 200;                          // 10
constexpr int OFF_DS2   = 256;                          // [l=15][m=29][k=60] = 26100
constexpr int OFF_DINV1 = OFF_DS2   + 26100;            // [k=30][l=15][m=29][n=29] = 378450
constexpr int OFF_DSO3F = OFF_DINV1 + 378450;           // [l=5][m=9][9][k=30] = 12150
constexpr int OFF_DOUT  = OFF_DSO3F + 12150;            // [k2=10][l=5][9][9] = 4050
constexpr int OFF_FSEL  = OFF_DOUT  + 4050;             // f2 [b=32][k=60][m=29] = 55680 f2
constexpr int OFF_XHAT  = OFF_FSEL  + 55680*2;          // f2 [b=32][l=15][m=29] = 13920 f2
constexpr int OFF_XHAT2 = OFF_XHAT  + 13920*2;          // f2 [l=5][288][450]    = 648000 f2
constexpr int OFF_FEATS = OFF_XHAT2 + 648000*2;         // [b=32][g=100] = 3200
constexpr int OFF_PSIT  = OFF_FEATS + 3200;             // f2 [g=50][l*29+n=435] = 21750 f2 (conj)
constexpr int OFF_R     = OFF_PSIT  + 21750*2;
// region R is reused:
//   FW    (f2 [b=32][fl=25][k=30][45] = 1,080,000 f2) live during k_s2so3/k_xhat2 passes
//   YHAT2 (f2 [l=5][288][900]         = 1,296,000 f2) live from k_yhat2 onward
constexpr int OFF_FW    = OFF_R;
constexpr int OFF_YH2   = OFF_R;
constexpr size_t WS_NEED = (size_t)(OFF_R + 2592000) * 4;   // ~18.4 MB

// ---------------- init: Wigner-d tables (double precision) ----------------
__constant__ double FCT[30] = {
  1.0, 1.0, 2.0, 6.0, 24.0, 120.0, 720.0, 5040.0, 40320.0, 362880.0,
  3628800.0, 39916800.0, 479001600.0, 6227020800.0, 87178291200.0,
  1307674368000.0, 20922789888000.0, 355687428096000.0, 6402373705728000.0,
  121645100408832000.0, 2432902008176640000.0, 51090942171709440000.0,
  1124000727777607680000.0, 25852016738884976640000.0,
  620448401733239439360000.0, 15511210043330985984000000.0,
  403291461126605635584000000.0, 10888869450418352160768000000.0,
  304888344611713860501504000000.0, 8841761993739701954543616000000.0 };

__device__ __forceinline__ int iabs_(int x)        { return x < 0 ? -x : x; }
__device__ __forceinline__ int imax_(int a, int b) { return a > b ? a : b; }
__device__ __forceinline__ int imin_(int a, int b) { return a < b ? a : b; }

__device__ double ipowd(double x, int e) {
  double r = 1.0;
  for (int i = 0; i < e; ++i) r *= x;
  return r;
}

// Wigner small-d element d^l_{mp,mm}(beta).
// c/s powers via recurrence P_{t+1} = P_t * (s^2/c^2) — one ipowd pair
// per ELEMENT instead of per t-term (verified R18).
__device__ double wig_d(int l, int mp, int mm, double beta) {
  double c = cos(0.5 * beta), s = sin(0.5 * beta);
  double pref = sqrt(FCT[l+mp] * FCT[l-mp] * FCT[l+mm] * FCT[l-mm]);
  int t0 = imax_(0, mm - mp), t1 = imin_(l + mm, l - mp);
  if (t0 > t1) return 0.0;
  double P = ipowd(c, 2*l + mm - mp - 2*t0) * ipowd(s, mp - mm + 2*t0);
  double ratio = (s*s) / (c*c);
  double acc = 0.0;
  for (int t = t0; t <= t1; ++t) {
    double term = P / (FCT[l+mm-t] * FCT[t] * FCT[mp-mm+t] * FCT[l-mp-t]);
    acc += ((mp - mm + t) & 1) ? -term : term;
    P *= ratio;
  }
  return pref * acc;
}

// Driscoll-Healy quadrature weight for bandwidth bq, sample k
__device__ double dh_w(int bq, int k) {
  double beta = PI_D * (2*k + 1) / (4.0 * bq);
  double ssum = 0.0;
  for (int j = 0; j < bq; ++j) ssum += sin((2*j + 1) * beta) / (2*j + 1);
  return (2.0 / bq) * sin(beta) * ssum;
}

// ---- one merged init kernel: ds2 | dinv1 | dso3f | dout | psit | trig ----
constexpr int SEG_DS2   = 0;
constexpr int SEG_DINV1 = SEG_DS2   + 26100;
constexpr int SEG_DSO3F = SEG_DINV1 + 378450;
constexpr int SEG_DOUT  = SEG_DSO3F + 12150;
constexpr int SEG_PSIT  = SEG_DOUT  + 4050;
constexpr int SEG_TRIG  = SEG_PSIT  + 21750;
constexpr int SEG_END   = SEG_TRIG  + 128;

__global__ void k_init_all(const float* __restrict__ ps2r,
                           const float* __restrict__ ps2i, float* W) {
  int id = blockIdx.x*256 + threadIdx.x;
  if (id >= SEG_END) return;
  if (id < SEG_DINV1) {            // D_S2[l][m][k]
    int t = id - SEG_DS2;
    int k = t % 60, m = (t/60) % 29, l = t/1740;
    int mp = m - 14;
    float v = 0.f;
    if (iabs_(mp) <= l) {
      double beta = PI_D * (2*k + 1) / 120.0;
      v = (float)(wig_d(l, mp, 0, beta) * dh_w(30, k) * (2.0*PI_D/60.0));
    }
    W[OFF_DS2 + t] = v;
  } else if (id < SEG_DSO3F) {     // DINV1[k][l][m][n]
    int t = id - SEG_DINV1;
    int n = t % 29, m = (t/29) % 29, l = (t/841) % 15, k = t/12615;
    int mp = m - 14, mm = n - 14;
    float v = 0.f;
    if (imax_(iabs_(mp), iabs_(mm)) <= l) {
      double beta = PI_D * (2*k + 1) / 60.0;
      v = (float)(wig_d(l, mp, mm, beta) * (2.0*l + 1.0) / (8.0*PI_D*PI_D));
    }
    W[OFF_DINV1 + t] = v;
  } else if (id < SEG_DOUT) {      // DSO3F[l][m][n][k]
    int t = id - SEG_DSO3F;
    int k = t % 30, n = (t/30) % 9, m = (t/270) % 9, l = t/2430;
    int mp = m - 4, mm = n - 4;
    float v = 0.f;
    if (imax_(iabs_(mp), iabs_(mm)) <= l) {
      double beta = PI_D * (2*k + 1) / 60.0;
      double sc = 2.0*PI_D/30.0;
      v = (float)(wig_d(l, mp, mm, beta) * dh_w(15, k) * sc * sc);
    }
    W[OFF_DSO3F + t] = v;
  } else if (id < SEG_PSIT) {      // DOUT[k2][l][m][n]
    int t = id - SEG_DOUT;
    int n = t % 9, m = (t/9) % 9, l = (t/81) % 5, k2 = t/405;
    int mp = m - 4, mm = n - 4;
    float v = 0.f;
    if (imax_(iabs_(mp), iabs_(mm)) <= l) {
      double beta = PI_D * (2*k2 + 1) / 20.0;
      v = (float)(wig_d(l, mp, mm, beta) * (2.0*l + 1.0) / (8.0*PI_D*PI_D));
    }
    W[OFF_DOUT + t] = v;
  } else if (id < SEG_TRIG) {      // PsiT[g][l*29+n] = conj(psi_s2)
    int t = id - SEG_PSIT;
    int g = t / 435, i = t % 435;
    ((float2*)(W + OFF_PSIT))[t] = make_float2(ps2r[i*50 + g], -ps2i[i*50 + g]);
  } else {                         // trig tables + W_INT
    int t = id - SEG_TRIG;
    if (t < 60) { W[OFF_C60+t] = (float)cos(2.0*PI_D*t/60.0); W[OFF_S60+t] = (float)sin(2.0*PI_D*t/60.0); }
    if (t < 30) { W[OFF_C30+t] = (float)cos(2.0*PI_D*t/30.0); W[OFF_S30+t] = (float)sin(2.0*PI_D*t/30.0); }
    if (t < 10) {
      W[OFF_C10+t] = (float)cos(2.0*PI_D*t/10.0); W[OFF_S10+t] = (float)sin(2.0*PI_D*t/10.0);
      double sc = 2.0*PI_D/10.0;
      W[OFF_WINT+t] = (float)(dh_w(5, t) * sc * sc);
    }
  }
}

// ---------------- pipeline ----------------
// K1a: Fsel[b][k][m] = sum_p x[b,k,p] * exp(-2pi*i*(m-14)*p/60)
__global__ void k_fsel(const float* __restrict__ x, float* W) {
  int id = blockIdx.x*256 + threadIdx.x;
  if (id >= 32*60*29) return;
  int m = id % 29, k = (id/29) % 60, b = id/1740;
  const float* c60 = W + OFF_C60;
  const float* s60 = W + OFF_S60;
  const float* xr = x + (b*60 + k)*60;
  int d = m - 14, q = 0;
  float ar = 0.f, ai = 0.f;
  for (int p = 0; p < 60; ++p) {
    float xv = xr[p];
    ar += xv * c60[q]; ai -= xv * s60[q];
    q += d; if (q >= 60) q -= 60; if (q < 0) q += 60;
  }
  ((float2*)(W + OFF_FSEL))[id] = make_float2(ar, ai);
}

// K1b: xhat[b][l][m] = sum_k D_S2[l][m][k] * Fsel[b][k][m]
__global__ void k_xhat(float* W) {
  int id = blockIdx.x*256 + threadIdx.x;
  if (id >= 32*15*29) return;
  int m = id % 29, l = (id/29) % 15, b = id/435;
  const float* D = W + OFF_DS2 + (l*29 + m)*60;
  const float2* F = (const float2*)(W + OFF_FSEL) + b*1740 + m;
  float ar = 0.f, ai = 0.f;
  for (int k = 0; k < 60; ++k) {
    float d = D[k]; float2 fv = F[k*29];
    ar += d*fv.x; ai += d*fv.y;
  }
  ((float2*)(W + OFF_XHAT))[id] = make_float2(ar, ai);
}

// K2: wave-private fused plane processor, radix-2 (30 = 2x15) in BOTH inverse
//  DFTs (R11 math, verified). FW stores ONLY Hermitian rows 4..8 (45 f2/plane)
//  — mirror rows reconstructed in k_xhat2 by conj; grid = (flgrp, b, k).
__global__ void __launch_bounds__(192, 5) k_s2so3(float* W, int g_base) {
  __shared__ float2 Xs[435];          // xhat[b][l][m]
  __shared__ float2 tw30s[30];        // w^q = (cos, sin)(2*pi*q/30)
  __shared__ float2 ABw[3][900];      // per-wave [r=15][p=2][m=30]; overlaid by Fa later
  int tid = threadIdx.x;
  int lane = tid & 63, w = tid >> 6;
  int k = blockIdx.z;                 // 0..29 (slowest -> Dg locality)
  int b = blockIdx.y;                 // 0..31
  int fl = blockIdx.x * 3 + w;        // 0..26; >=25 idle
  int g = g_base + fl;

  {
    const float2* XH = (const float2*)(W + OFF_XHAT);
    for (int i = tid; i < 435; i += 192) Xs[i] = XH[b*435 + i];
    if (tid < 30) tw30s[tid] = make_float2(W[OFF_C30+tid], W[OFF_S30+tid]);
  }
  __syncthreads();                    // the only block barrier
  if (fl >= 25) return;               // idle wave-slots exit

  const float* __restrict__ Dg = W + OFF_DINV1 + k*12615;               // L2/L1
  const float2* __restrict__ Qg = (const float2*)(W + OFF_PSIT) + g*435; // L2
  float2* ABs = ABw[w];

  // --- AB phase: unit e = m*15 + r computes G pair (n1=r+14, n2=r-1),
  //     stores A = g1+g2 at [r][0][m], Btilde = (g1-g2)*w^r at [r][1][m].
  //     m=29 and r=0's g2 vanish naturally via lmin >= 15 (empty l-loop).
  {
    int m = lane / 15, r = lane - (lane/15)*15;
    for (int e = lane; e < 450; e += 64) {
      int am = iabs_(m - 14);
      int n1 = r + 14;
      float g1r = 0.f, g1i = 0.f;
      int lmin1 = imax_(am, r);
      for (int l = lmin1; l < 15; ++l) {
        float d = Dg[l*841 + m*29 + n1];
        float2 X = Xs[l*29 + m];
        float2 Q = Qg[l*29 + n1];
        g1r += d*(X.x*Q.x - X.y*Q.y);
        g1i += d*(X.x*Q.y + X.y*Q.x);
      }
      int n2 = r - 1;                       // invalid for r=0, but loop is empty then
      float g2r = 0.f, g2i = 0.f;
      int lmin2 = imax_(am, 15 - r);
      for (int l = lmin2; l < 15; ++l) {
        float d = Dg[l*841 + m*29 + n2];
        float2 X = Xs[l*29 + m];
        float2 Q = Qg[l*29 + n2];
        g2r += d*(X.x*Q.x - X.y*Q.y);
        g2i += d*(X.x*Q.y + X.y*Q.x);
      }
      float2 tw = tw30s[r];
      float br = g1r - g2r, bi = g1i - g2i;
      ABs[(r*2+0)*30 + m] = make_float2(g1r + g2r, g1i + g2i);
      ABs[(r*2+1)*30 + m] = make_float2(br*tw.x - bi*tw.y, br*tw.y + bi*tw.x);
      r += 4; m += 4; if (r >= 15) { r -= 15; m += 1; }   // 64 = 4*15 + 4
    }
  }
  WAVE_SYNC();

  // --- T phase: lane (j = lane>>1, half = lane&1); j = 2t + p ---
  int j = lane >> 1, half = lane & 1;
  bool act = (j < 30);
  int p = j & 1, t = j >> 1;
  int m0 = half * 15;                 // half0: m 0..14, half1: m 15..29 (29 = zero)
  const float2* Crow = ABs + p*30 + m0;
  float tr[15], ti[15];
  #pragma unroll
  for (int mi = 0; mi < 15; ++mi) { tr[mi] = 0.f; ti[mi] = 0.f; }
  if (act) {
    int q = 0, step = 2*t;            // nu^{tr} = tw30s[(2tr) mod 30]
    for (int r = 0; r < 15; ++r) {
      float2 tw = tw30s[q];
      #pragma unroll
      for (int mi = 0; mi < 15; ++mi) {
        float2 cv = Crow[r*60 + mi];
        tr[mi] += cv.x*tw.x - cv.y*tw.y;
        ti[mi] += cv.x*tw.y + cv.y*tw.x;
      }
      q += step; if (q >= 30) q -= 30;
    }
  }

  // --- exchange + m-direction radix-2 pre-combine (pairs align at same reg) ---
  // half0 builds Ah[r], half1 builds Bh[r]*w^r; r=0 term = T[14] (half0 reg 14)
  float cr[15], ci[15];
  if (act) {
    float sgn = half ? -1.f : 1.f;
    #pragma unroll
    for (int i = 0; i < 14; ++i) {
      float otr = __shfl_xor(tr[i], 1);
      float oti = __shfl_xor(ti[i], 1);
      float vr = fmaf(sgn, otr, tr[i]) * (half ? -sgn : 1.f); // half0: tr+otr; half1: tr-otr
      float vi = fmaf(sgn, oti, ti[i]) * (half ? -sgn : 1.f);
      float2 twc = half ? tw30s[i+1] : make_float2(1.f, 0.f);
      cr[i+1] = vr*twc.x - vi*twc.y;
      ci[i+1] = vr*twc.y + vi*twc.x;
    }
    float otr14 = __shfl_xor(tr[14], 1);
    float oti14 = __shfl_xor(ti[14], 1);
    cr[0] = half ? otr14 : tr[14];
    ci[0] = half ? oti14 : ti[14];
  } else {
    #pragma unroll
    for (int i = 0; i < 15; ++i) { cr[i] = 0.f; ci[i] = 0.f; }
  }

  // --- h (own parity: a = 2s + half) + Fa partials for m2 = 4..8 ---
  float far[5], fai[5];
  #pragma unroll
  for (int u = 0; u < 5; ++u) { far[u] = 0.f; fai[u] = 0.f; }
  if (act) {
    for (int s = 0; s < 15; ++s) {
      int a = 2*s + half;
      float hp = 0.f;
      int q = 0, step = 2*s;
      #pragma unroll
      for (int r = 0; r < 15; ++r) {
        float2 tw = tw30s[q];
        hp += cr[r]*tw.x - ci[r]*tw.y;
        q += step; if (q >= 30) q -= 30;
      }
      float hv = fmaxf(hp, 0.f);
      int q2 = 0;                       // (m2-4)*a mod 30, step a
      #pragma unroll
      for (int u = 0; u < 5; ++u) {
        float2 tw = tw30s[q2];
        far[u] += hv*tw.x;
        fai[u] -= hv*tw.y;
        q2 += a; if (q2 >= 30) q2 -= 30;
      }
    }
    // combine even/odd-a partials across the lane pair
    #pragma unroll
    for (int u = 0; u < 5; ++u) {
      far[u] += __shfl_xor(far[u], 1);
      fai[u] += __shfl_xor(fai[u], 1);
    }
  }
  WAVE_SYNC();   // all reads of ABs done; safe to overlay Fa

  // --- write Fa rows 4..8 (overlay on dead ABs region) ---
  float2* Fas = ABs;
  if (act && half == 0) {
    #pragma unroll
    for (int u = 0; u < 5; ++u)
      Fas[(4 + u)*30 + j] = make_float2(far[u], fai[u]);
  }
  WAVE_SYNC();

  // --- FW rows 4..8 only (45 entries); mirror handled in k_xhat2 ---
  float2* FW = (float2*)(W + OFF_FW);
  size_t pbase = ((size_t)(b*25 + fl)*30 + k)*45;
  if (lane < 45) {
    int m2 = 4 + lane/9, n2 = lane % 9;
    int d = (n2 - 4 + 30) % 30, q = 0;
    float fr = 0.f, fi = 0.f;
    for (int jj = 0; jj < 30; ++jj) {
      float2 fv = Fas[m2*30 + jj];
      float2 tw = tw30s[q];
      fr += fv.x*tw.x + fv.y*tw.y;
      fi += fv.y*tw.x - fv.x*tw.y;
      q += d; if (q >= 30) q -= 30;
    }
    FW[pbase + lane] = make_float2(fr, fi);
  }
}

// K3: xhat2[l][b*9+m2][f*9+n2] = sum_k DSO3F[l][m2][n2][k] * FW(k)[m2][n2]
//  FW stores rows 4..8 only; m2<4 reconstructed via FW[m2][n2]=conj(FW[8-m2][8-n2]).
__global__ void k_xhat2(float* W, int g_base) {
  int id = blockIdx.x*256 + threadIdx.x;
  if (id >= 324000) return;
  int n2 = id % 9, fl = (id/9) % 25, m2 = (id/225) % 9, b = (id/2025) % 32, l = id/64800;
  int f = g_base + fl;
  const float* D = W + OFF_DSO3F + (l*81 + m2*9 + n2)*30;
  bool mir = (m2 < 4);
  int ms = mir ? (4 - m2) : (m2 - 4);     // storage row (0..4 maps m2 4..8)
  int cs = mir ? (8 - n2) : n2;
  const float2* FWp = (const float2*)(W + OFF_FW)
                    + (size_t)(b*25 + fl)*30*45 + ms*9 + cs;
  float ar = 0.f, ai = 0.f;
  for (int k = 0; k < 30; ++k) {
    float d = D[k]; float2 fv = FWp[(size_t)k*45];
    ar += d*fv.x; ai += d*fv.y;
  }
  if (mir) ai = -ai;
  ((float2*)(W + OFF_XHAT2))[(l*288 + b*9 + m2)*450 + f*9 + n2] = make_float2(ar, ai);
}

// K4: per-l complex GEMM C[288][900] = A[288][450] * B[450][900]; K-tile 30
__global__ void __launch_bounds__(256) k_yhat2(const float* __restrict__ p3r,
                                               const float* __restrict__ p3i,
                                               float* W) {
  __shared__ float2 As[32][30];
  __shared__ float2 Bs[30][64];
  int l  = blockIdx.z;
  int r0 = blockIdx.y * 32;
  int c0 = blockIdx.x * 64;
  int tid = threadIdx.x;
  const float2* A = (const float2*)(W + OFF_XHAT2) + (size_t)l*288*450;
  float2*       C = (float2*)(W + OFF_YH2)         + (size_t)l*288*900;
  int tr = tid / 16, tc = tid % 16;
  float2 acc[2][4];
  #pragma unroll
  for (int i = 0; i < 2; ++i)
    #pragma unroll
    for (int j = 0; j < 4; ++j) acc[i][j] = make_float2(0.f, 0.f);

  for (int k0 = 0; k0 < 450; k0 += 30) {
    for (int e = tid; e < 960; e += 256) {
      int i = e / 30, kk = e % 30;
      As[i][kk] = A[(r0 + i)*450 + k0 + kk];
    }
    for (int e = tid; e < 1920; e += 256) {
      int kkr = e / 64, j = e % 64;
      int c = k0 + kkr;
      int f = c / 9, kk = c % 9;
      int cc = c0 + j;
      float2 v = make_float2(0.f, 0.f);
      if (cc < 900) {
        int n = cc / 100, g = cc % 100;
        int idx = (((l*9 + n)*9 + kk)*50 + f)*100 + g;
        v = make_float2(p3r[idx], -p3i[idx]);
      }
      Bs[kkr][j] = v;
    }
    __syncthreads();
    #pragma unroll
    for (int kk = 0; kk < 30; ++kk) {
      float2 a0 = As[tr*2][kk], a1 = As[tr*2+1][kk];
      float2 aa[2] = {a0, a1};
      float2 b0 = Bs[kk][tc*4], b1 = Bs[kk][tc*4+1], b2 = Bs[kk][tc*4+2], b3 = Bs[kk][tc*4+3];
      float2 bb[4] = {b0, b1, b2, b3};
      #pragma unroll
      for (int i = 0; i < 2; ++i)
        #pragma unroll
        for (int j = 0; j < 4; ++j) {
          acc[i][j].x += aa[i].x*bb[j].x - aa[i].y*bb[j].y;
          acc[i][j].y += aa[i].x*bb[j].y + aa[i].y*bb[j].x;
        }
    }
    __syncthreads();
  }
  #pragma unroll
  for (int i = 0; i < 2; ++i) {
    int r = r0 + tr*2 + i;
    #pragma unroll
    for (int j = 0; j < 4; ++j) {
      int cc = c0 + tc*4 + j;
      if (cc < 900) C[r*900 + cc] = acc[i][j];
    }
  }
}

// K5: per (b,g): G2 -> 9x9->10x10 ifft2 -> relu -> weighted sum over (k2,a,j)
__global__ void __launch_bounds__(128) k_so3out(float* W) {
  __shared__ float2 Ys[405];
  __shared__ float2 G2s[81];
  __shared__ float2 T2s[90];
  __shared__ float  red[128];
  __shared__ float  c10s[10], s10s[10];
  int g = blockIdx.x, b = blockIdx.y, tid = threadIdx.x;
  const float2* C = (const float2*)(W + OFF_YH2);
  for (int e = tid; e < 405; e += 128) {
    int l = e / 81, r = e % 81, m = r / 9, n = r % 9;
    Ys[e] = C[((size_t)l*288 + b*9 + m)*900 + n*100 + g];
  }
  if (tid < 10) { c10s[tid] = W[OFF_C10+tid]; s10s[tid] = W[OFF_S10+tid]; }
  __syncthreads();
  float pacc = 0.f;
  for (int k2 = 0; k2 < 10; ++k2) {
    float wi = W[OFF_WINT + k2];
    if (tid < 81) {
      int m = tid / 9, n = tid % 9;
      int lmin = imax_(iabs_(m-4), iabs_(n-4));
      float ar = 0.f, ai = 0.f;
      for (int l = lmin; l < 5; ++l) {
        float d = W[OFF_DOUT + (k2*5 + l)*81 + tid];
        float2 y = Ys[l*81 + tid];
        ar += d*y.x; ai += d*y.y;
      }
      G2s[tid] = make_float2(ar, ai);
    }
    __syncthreads();
    if (tid < 90) {
      int m = tid / 10, j = tid % 10;
      int q = ((-4*j) % 10 + 10) % 10;
      float tr = 0.f, ti = 0.f;
      for (int n = 0; n < 9; ++n) {
        float2 gv = G2s[m*9 + n];
        float c = c10s[q], s = s10s[q];
        tr += gv.x*c - gv.y*s; ti += gv.x*s + gv.y*c;
        q += j; if (q >= 10) q -= 10;
      }
      T2s[tid] = make_float2(tr, ti);
    }
    __syncthreads();
    if (tid < 100) {
      int a = tid / 10, j = tid % 10;
      int q = ((-4*a) % 10 + 10) % 10;
      float hv = 0.f;
      for (int m = 0; m < 9; ++m) {
        float2 tv = T2s[m*10 + j];
        hv += tv.x*c10s[q] - tv.y*s10s[q];
        q += a; if (q >= 10) q -= 10;
      }
      pacc += wi * fmaxf(hv, 0.f);
    }
    __syncthreads();
  }
  red[tid] = pacc;
  __syncthreads();
  for (int s = 64; s > 0; s >>= 1) {
    if (tid < s) red[tid] += red[tid + s];
    __syncthreads();
  }
  if (tid == 0) W[OFF_FEATS + b*100 + g] = red[0];
}

// K6: out[b][c] = bias[c] + sum_g feats[b][g] * w[c][g]
__global__ void k_out(const float* W, const float* __restrict__ w,
                      const float* __restrict__ bias, float* out) {
  int tid = threadIdx.x;
  if (tid >= 320) return;
  int bb = tid / 10, c = tid % 10;
  float acc = bias[c];
  const float* f  = W + OFF_FEATS + bb*100;
  const float* wr = w + c*100;
  for (int g = 0; g < 100; ++g) acc += f[g]*wr[g];
  out[tid] = acc;
}

extern "C" void kernel_launch(void* const* d_in, const int* in_sizes, int n_in,
                              void* d_out, int out_size, void* d_ws, size_t ws_size,
                              hipStream_t stream) {
  (void)in_sizes; (void)n_in; (void)out_size;
  if (ws_size < WS_NEED) return;  // fail loud: output stays poisoned
  const float* x    = (const float*)d_in[0];
  const float* p2r  = (const float*)d_in[1];
  const float* p2i  = (const float*)d_in[2];
  const float* p3r  = (const float*)d_in[3];
  const float* p3i  = (const float*)d_in[4];
  const float* wlin = (const float*)d_in[5];
  const float* blin = (const float*)d_in[6];
  float* W   = (float*)d_ws;
  float* out = (float*)d_out;

  k_init_all <<<(SEG_END + 255)/256, 256, 0, stream>>>(p2r, p2i, W);
  k_fsel     <<<218, 256, 0, stream>>>(x, W);
  k_xhat     <<<55,  256, 0, stream>>>(W);
  for (int gb = 0; gb < 50; gb += 25) {
    k_s2so3 <<<dim3(9, 32, 30), 192, 0, stream>>>(W, gb);
    k_xhat2 <<<1266, 256, 0, stream>>>(W, gb);
  }
  k_yhat2  <<<dim3(15, 9, 5), 256, 0, stream>>>(p3r, p3i, W);
  k_so3out <<<dim3(100, 32), 128, 0, stream>>>(W);
  k_out    <<<1, 320, 0, stream>>>(W, wlin, blin, out);
}